// Round 2
// baseline (577.372 us; speedup 1.0000x reference)
//
#include <hip/hip_runtime.h>

#define B_ 2
#define N_ 6
#define D_ 41
#define H_ 16
#define W_ 44
#define C_ 64
#define X_ 200
#define Y_ 200
#define NPTS (B_*N_*D_*H_*W_)   // 346368
#define NBN (B_*N_)             // 12
#define NCELL (B_*X_*Y_)        // 80000
#define MAT_STRIDE 24           // doubles per (b,n)

__device__ inline void inv3x3(const double m[9], double out[9]) {
    double a=m[0],b=m[1],c=m[2],d=m[3],e=m[4],f=m[5],g=m[6],h=m[7],i=m[8];
    double A  =  (e*i - f*h);
    double Bm = -(d*i - f*g);
    double Cm =  (d*h - e*g);
    double det = a*A + b*Bm + c*Cm;
    double id = 1.0/det;
    out[0] = A*id;   out[1] = -(b*i - c*h)*id; out[2] =  (b*f - c*e)*id;
    out[3] = Bm*id;  out[4] =  (a*i - c*g)*id; out[5] = -(a*f - c*d)*id;
    out[6] = Cm*id;  out[7] = -(a*h - b*g)*id; out[8] =  (a*e - b*d)*id;
}

// One thread per (b,n): inv(post_rots), comb = rot(inv(extr)) @ inv(K), trans.
__global__ void prep_kernel(const float* __restrict__ post_rots,
                            const float* __restrict__ intr,
                            const float* __restrict__ extr,
                            double* __restrict__ mats) {
    int bn = threadIdx.x;
    if (bn >= NBN) return;

    double pr[9], prinv[9], kk[9], kin[9];
    for (int i=0;i<9;i++) pr[i] = (double)post_rots[bn*9+i];
    inv3x3(pr, prinv);
    for (int i=0;i<9;i++) kk[i] = (double)intr[bn*9+i];
    inv3x3(kk, kin);

    double a[4][8];
    for (int i=0;i<4;i++)
        for (int j=0;j<4;j++){ a[i][j] = (double)extr[bn*16+i*4+j]; a[i][4+j] = (i==j)?1.0:0.0; }
    for (int col=0; col<4; col++){
        int piv = col; double best = fabs(a[col][col]);
        for (int r=col+1;r<4;r++){ double v=fabs(a[r][col]); if (v>best){best=v;piv=r;} }
        if (piv != col) for (int j=0;j<8;j++){ double t=a[col][j]; a[col][j]=a[piv][j]; a[piv][j]=t; }
        double ip = 1.0/a[col][col];
        for (int j=0;j<8;j++) a[col][j] *= ip;
        for (int r=0;r<4;r++){
            if (r==col) continue;
            double f = a[r][col];
            for (int j=0;j<8;j++) a[r][j] -= f*a[col][j];
        }
    }
    double rot[9], trans[3];
    for (int i=0;i<3;i++){ for (int j=0;j<3;j++) rot[i*3+j]=a[i][4+j]; trans[i]=a[i][4+3]; }
    double comb[9];
    for (int i=0;i<3;i++) for (int j=0;j<3;j++)
        comb[i*3+j] = rot[i*3+0]*kin[0+j] + rot[i*3+1]*kin[3+j] + rot[i*3+2]*kin[6+j];

    double* o = mats + (size_t)bn*MAT_STRIDE;
    for (int i=0;i<9;i++) o[i]   = prinv[i];
    for (int i=0;i<9;i++) o[9+i] = comb[i];
    for (int i=0;i<3;i++) o[18+i]= trans[i];
}

// One THREAD per point: cell id (or -1) + histogram.
__global__ __launch_bounds__(256)
void geom_kernel(const float* __restrict__ post_trans,
                 const float* __restrict__ frustum,
                 const float* __restrict__ bev_res,
                 const float* __restrict__ bev_start,
                 const double* __restrict__ mats,
                 int* __restrict__ rank, int* __restrict__ hist) {
    int p = blockIdx.x * blockDim.x + threadIdx.x;
    if (p >= NPTS) return;

    int w = p % W_; int t = p / W_;
    int h = t % H_;  t /= H_;
    int d = t % D_;  t /= D_;
    int bn = t;      int b = bn / N_;

    const double* M = mats + (size_t)bn*MAT_STRIDE;
    int fidx = ((d*H_ + h)*W_ + w)*3;
    double fx = (double)frustum[fidx+0];
    double fy = (double)frustum[fidx+1];
    double fz = (double)frustum[fidx+2];

    double px = fx - (double)post_trans[bn*3+0];
    double py = fy - (double)post_trans[bn*3+1];
    double pz = fz - (double)post_trans[bn*3+2];

    double q0 = M[0]*px + M[1]*py + M[2]*pz;
    double q1 = M[3]*px + M[4]*py + M[5]*pz;
    double q2 = M[6]*px + M[7]*py + M[8]*pz;

    double r0 = q0*q2, r1 = q1*q2, r2 = q2;

    double gx = M[9]*r0  + M[10]*r1 + M[11]*r2 + M[18];
    double gy = M[12]*r0 + M[13]*r1 + M[14]*r2 + M[19];
    double gz = M[15]*r0 + M[16]*r1 + M[17]*r2 + M[20];

    double resx = (double)bev_res[0], resy = (double)bev_res[1], resz = (double)bev_res[2];
    double sx = (double)bev_start[0] - resx*0.5;
    double sy = (double)bev_start[1] - resy*0.5;
    double sz = (double)bev_start[2] - resz*0.5;

    int cx = (int)((gx - sx)/resx);
    int cy = (int)((gy - sy)/resy);
    int cz = (int)((gz - sz)/resz);

    int cell = -1;
    if (cx >= 0 && cx < X_ && cy >= 0 && cy < Y_ && cz == 0) {
        cell = (b*X_ + cx)*Y_ + cy;
        atomicAdd(&hist[cell], 1);
    }
    rank[p] = cell;
}

// Single-block scan of hist[NCELL] -> offs[NCELL+1], cursor[NCELL].
__global__ __launch_bounds__(1024)
void prefix_kernel(const int* __restrict__ hist,
                   int* __restrict__ offs, int* __restrict__ cursor) {
    __shared__ int sums[1024];
    const int PER = (NCELL + 1023) / 1024;   // 79
    int t = threadIdx.x;
    int lo = t*PER, hi = min(lo+PER, NCELL);
    int s = 0;
    for (int i=lo;i<hi;i++) s += hist[i];
    sums[t] = s;
    __syncthreads();
    for (int off=1; off<1024; off<<=1){
        int v = (t>=off) ? sums[t-off] : 0;
        __syncthreads();
        sums[t] += v;
        __syncthreads();
    }
    int run = (t==0) ? 0 : sums[t-1];
    for (int i=lo;i<hi;i++){ offs[i]=run; cursor[i]=run; run += hist[i]; }
    if (t == 1023) offs[NCELL] = sums[1023];
}

// Counting-sort point ids into per-cell lists.
__global__ __launch_bounds__(256)
void fill_kernel(const int* __restrict__ rank,
                 int* __restrict__ cursor, int* __restrict__ plist) {
    int p = blockIdx.x * blockDim.x + threadIdx.x;
    if (p >= NPTS) return;
    int cell = rank[p];
    if (cell >= 0) {
        int pos = atomicAdd(&cursor[cell], 1);
        plist[pos] = p;
    }
}

// One wave per cell (lane = channel); block = (b, x, y-half of 100 cells).
// Accumulate in registers, transpose via LDS, write (B,C,X,Y) coalesced.
__global__ __launch_bounds__(256)
void gather_kernel(const float* __restrict__ feat,
                   const int* __restrict__ offs,
                   const int* __restrict__ plist,
                   float* __restrict__ out) {
    __shared__ float tile[100][65];
    int blk = blockIdx.x;            // 0 .. B_*X_*2-1
    int yh  = blk & 1;
    int x   = (blk >> 1) % X_;
    int b   = (blk >> 1) / X_;
    int wid = threadIdx.x >> 6, lane = threadIdx.x & 63;
    int y0  = yh * 100;

    for (int yy = wid; yy < 100; yy += 4) {
        int cell = (b*X_ + x)*Y_ + (y0 + yy);
        int s = offs[cell], e = offs[cell+1];
        float acc = 0.f;
        for (int i = s; i < e; ++i) {
            int p = plist[i];
            acc += feat[(size_t)p*C_ + lane];
        }
        tile[yy][lane] = acc;
    }
    __syncthreads();
    for (int c = wid; c < C_; c += 4) {
        for (int yy = lane; yy < 100; yy += 64) {
            out[(((size_t)b*C_ + c)*X_ + x)*Y_ + y0 + yy] = tile[yy][c];
        }
    }
}

// Fallback (tiny ws): direct atomics into (B,C,X,Y).
__global__ __launch_bounds__(256)
void scatter_fallback(const float* __restrict__ feat,
                      const int* __restrict__ rank,
                      float* __restrict__ dst) {
    int tid  = blockIdx.x * blockDim.x + threadIdx.x;
    int wave = tid >> 6;
    int lane = tid & 63;
    if (wave >= NPTS) return;
    int cell = rank[wave];
    if (cell < 0) return;
    int b = cell / (X_*Y_);
    int xy = cell % (X_*Y_);
    float v = feat[(size_t)wave*C_ + lane];
    atomicAdd(&dst[((size_t)(b*C_ + lane))*(X_*Y_) + xy], v);
}

extern "C" void kernel_launch(void* const* d_in, const int* in_sizes, int n_in,
                              void* d_out, int out_size, void* d_ws, size_t ws_size,
                              hipStream_t stream) {
    const float* feat       = (const float*)d_in[0];
    const float* post_trans = (const float*)d_in[1];
    const float* post_rots  = (const float*)d_in[2];
    const float* intr       = (const float*)d_in[3];
    const float* extr       = (const float*)d_in[4];
    const float* frustum    = (const float*)d_in[5];
    const float* bev_res    = (const float*)d_in[6];
    const float* bev_start  = (const float*)d_in[7];
    float* out = (float*)d_out;

    // ws layout
    char* base = (char*)d_ws;
    double* mats  = (double*)base;                         size_t off = 4096;
    int* rank     = (int*)(base + off);                    off += (size_t)NPTS*4;
    int* hist     = (int*)(base + off);                    off += (size_t)NCELL*4;
    int* offs     = (int*)(base + off);                    off += (size_t)(NCELL+1)*4 + 4;
    int* cursor   = (int*)(base + off);                    off += (size_t)NCELL*4;
    int* plist    = (int*)(base + off);                    off += (size_t)NPTS*4;
    bool have_ws = (ws_size >= off);

    hipLaunchKernelGGL(prep_kernel, dim3(1), dim3(16), 0, stream,
                       post_rots, intr, extr, mats);

    const int pt_blocks = (NPTS + 255) / 256;

    if (have_ws) {
        hipMemsetAsync(hist, 0, (size_t)NCELL*4, stream);
        geom_kernel<<<pt_blocks, 256, 0, stream>>>(post_trans, frustum, bev_res,
                                                   bev_start, mats, rank, hist);
        prefix_kernel<<<1, 1024, 0, stream>>>(hist, offs, cursor);
        fill_kernel<<<pt_blocks, 256, 0, stream>>>(rank, cursor, plist);
        gather_kernel<<<B_*X_*2, 256, 0, stream>>>(feat, offs, plist, out);
    } else {
        // minimal fallback: geom (rank only, reuse hist ptr? no ws) — direct atomics
        // ws too small even for rank: recompute per-wave like R0 is gone; assume at
        // least rank fits (1.4 MB); else nothing we can do.
        hipMemsetAsync(out, 0, (size_t)out_size*sizeof(float), stream);
        geom_kernel<<<pt_blocks, 256, 0, stream>>>(post_trans, frustum, bev_res,
                                                   bev_start, mats, rank, hist);
        scatter_fallback<<<(NPTS*64 + 255)/256, 256, 0, stream>>>(feat, rank, out);
    }
}

// Round 3
// 376.164 us; speedup vs baseline: 1.5349x; 1.5349x over previous
//
#include <hip/hip_runtime.h>

#define B_ 2
#define N_ 6
#define D_ 41
#define H_ 16
#define W_ 44
#define C_ 64
#define X_ 200
#define Y_ 200
#define NPTS (B_*N_*D_*H_*W_)   // 346368
#define NBN (B_*N_)             // 12
#define NCELL (B_*X_*Y_)        // 80000
#define MAT_STRIDE 24           // doubles per (b,n)
#define CHUNK 32                // sorted points per wave in gather

__device__ inline void inv3x3(const double m[9], double out[9]) {
    double a=m[0],b=m[1],c=m[2],d=m[3],e=m[4],f=m[5],g=m[6],h=m[7],i=m[8];
    double A  =  (e*i - f*h);
    double Bm = -(d*i - f*g);
    double Cm =  (d*h - e*g);
    double det = a*A + b*Bm + c*Cm;
    double id = 1.0/det;
    out[0] = A*id;   out[1] = -(b*i - c*h)*id; out[2] =  (b*f - c*e)*id;
    out[3] = Bm*id;  out[4] =  (a*i - c*g)*id; out[5] = -(a*f - c*d)*id;
    out[6] = Cm*id;  out[7] = -(a*h - b*g)*id; out[8] =  (a*e - b*d)*id;
}

// One thread per (b,n): inv(post_rots), comb = rot(inv(extr)) @ inv(K), trans.
__global__ void prep_kernel(const float* __restrict__ post_rots,
                            const float* __restrict__ intr,
                            const float* __restrict__ extr,
                            double* __restrict__ mats) {
    int bn = threadIdx.x;
    if (bn >= NBN) return;

    double pr[9], prinv[9], kk[9], kin[9];
    for (int i=0;i<9;i++) pr[i] = (double)post_rots[bn*9+i];
    inv3x3(pr, prinv);
    for (int i=0;i<9;i++) kk[i] = (double)intr[bn*9+i];
    inv3x3(kk, kin);

    double a[4][8];
    for (int i=0;i<4;i++)
        for (int j=0;j<4;j++){ a[i][j] = (double)extr[bn*16+i*4+j]; a[i][4+j] = (i==j)?1.0:0.0; }
    for (int col=0; col<4; col++){
        int piv = col; double best = fabs(a[col][col]);
        for (int r=col+1;r<4;r++){ double v=fabs(a[r][col]); if (v>best){best=v;piv=r;} }
        if (piv != col) for (int j=0;j<8;j++){ double t=a[col][j]; a[col][j]=a[piv][j]; a[piv][j]=t; }
        double ip = 1.0/a[col][col];
        for (int j=0;j<8;j++) a[col][j] *= ip;
        for (int r=0;r<4;r++){
            if (r==col) continue;
            double f = a[r][col];
            for (int j=0;j<8;j++) a[r][j] -= f*a[col][j];
        }
    }
    double rot[9], trans[3];
    for (int i=0;i<3;i++){ for (int j=0;j<3;j++) rot[i*3+j]=a[i][4+j]; trans[i]=a[i][4+3]; }
    double comb[9];
    for (int i=0;i<3;i++) for (int j=0;j<3;j++)
        comb[i*3+j] = rot[i*3+0]*kin[0+j] + rot[i*3+1]*kin[3+j] + rot[i*3+2]*kin[6+j];

    double* o = mats + (size_t)bn*MAT_STRIDE;
    for (int i=0;i<9;i++) o[i]   = prinv[i];
    for (int i=0;i<9;i++) o[9+i] = comb[i];
    for (int i=0;i<3;i++) o[18+i]= trans[i];
}

// One THREAD per point: cell id (or -1) + histogram.
__global__ __launch_bounds__(256)
void geom_kernel(const float* __restrict__ post_trans,
                 const float* __restrict__ frustum,
                 const float* __restrict__ bev_res,
                 const float* __restrict__ bev_start,
                 const double* __restrict__ mats,
                 int* __restrict__ rank, int* __restrict__ hist) {
    int p = blockIdx.x * blockDim.x + threadIdx.x;
    if (p >= NPTS) return;

    int w = p % W_; int t = p / W_;
    int h = t % H_;  t /= H_;
    int d = t % D_;  t /= D_;
    int bn = t;      int b = bn / N_;

    const double* M = mats + (size_t)bn*MAT_STRIDE;
    int fidx = ((d*H_ + h)*W_ + w)*3;
    double fx = (double)frustum[fidx+0];
    double fy = (double)frustum[fidx+1];
    double fz = (double)frustum[fidx+2];

    double px = fx - (double)post_trans[bn*3+0];
    double py = fy - (double)post_trans[bn*3+1];
    double pz = fz - (double)post_trans[bn*3+2];

    double q0 = M[0]*px + M[1]*py + M[2]*pz;
    double q1 = M[3]*px + M[4]*py + M[5]*pz;
    double q2 = M[6]*px + M[7]*py + M[8]*pz;

    double r0 = q0*q2, r1 = q1*q2, r2 = q2;

    double gx = M[9]*r0  + M[10]*r1 + M[11]*r2 + M[18];
    double gy = M[12]*r0 + M[13]*r1 + M[14]*r2 + M[19];
    double gz = M[15]*r0 + M[16]*r1 + M[17]*r2 + M[20];

    double resx = (double)bev_res[0], resy = (double)bev_res[1], resz = (double)bev_res[2];
    double sx = (double)bev_start[0] - resx*0.5;
    double sy = (double)bev_start[1] - resy*0.5;
    double sz = (double)bev_start[2] - resz*0.5;

    int cx = (int)((gx - sx)/resx);
    int cy = (int)((gy - sy)/resy);
    int cz = (int)((gz - sz)/resz);

    int cell = -1;
    if (cx >= 0 && cx < X_ && cy >= 0 && cy < Y_ && cz == 0) {
        cell = (b*X_ + cx)*Y_ + cy;
        atomicAdd(&hist[cell], 1);
    }
    rank[p] = cell;
}

// Single-block scan of hist[NCELL] -> offs[NCELL+1], cursor[NCELL].
__global__ __launch_bounds__(1024)
void prefix_kernel(const int* __restrict__ hist,
                   int* __restrict__ offs, int* __restrict__ cursor) {
    __shared__ int sums[1024];
    const int PER = (NCELL + 1023) / 1024;   // 79
    int t = threadIdx.x;
    int lo = t*PER, hi = min(lo+PER, NCELL);
    int s = 0;
    for (int i=lo;i<hi;i++) s += hist[i];
    sums[t] = s;
    __syncthreads();
    for (int off=1; off<1024; off<<=1){
        int v = (t>=off) ? sums[t-off] : 0;
        __syncthreads();
        sums[t] += v;
        __syncthreads();
    }
    int run = (t==0) ? 0 : sums[t-1];
    for (int i=lo;i<hi;i++){ offs[i]=run; cursor[i]=run; run += hist[i]; }
    if (t == 1023) offs[NCELL] = sums[1023];
}

// Counting-sort: point ids AND cell ids into sorted lists.
__global__ __launch_bounds__(256)
void fill_kernel(const int* __restrict__ rank,
                 int* __restrict__ cursor,
                 int* __restrict__ plist, int* __restrict__ clist) {
    int p = blockIdx.x * blockDim.x + threadIdx.x;
    if (p >= NPTS) return;
    int cell = rank[p];
    if (cell >= 0) {
        int pos = atomicAdd(&cursor[cell], 1);
        plist[pos] = p;
        clist[pos] = cell;
    }
}

// Load-balanced segmented reduction over the sorted list.
// One wave per CHUNK sorted points; lane = channel. Flush on cell change.
__global__ __launch_bounds__(256)
void gather2_kernel(const float* __restrict__ feat,
                    const int* __restrict__ clist,
                    const int* __restrict__ plist,
                    const int* __restrict__ total_ptr,
                    float* __restrict__ out) {
    int gwave = (int)((blockIdx.x * blockDim.x + threadIdx.x) >> 6);
    int lane  = threadIdx.x & 63;
    int total = total_ptr[0];
    int i0 = gwave * CHUNK;
    if (i0 >= total) return;
    int n = min(CHUNK, total - i0);

    int cl = -1, pl = 0;
    if (lane < n) { cl = clist[i0 + lane]; pl = plist[i0 + lane]; }

    int cur = __shfl(cl, 0);
    float acc = 0.f;

    if (n == CHUNK) {
        #pragma unroll
        for (int i = 0; i < CHUNK; ++i) {
            int cell = __shfl(cl, i);
            int p    = __shfl(pl, i);
            if (cell != cur) {
                int b = cur / (X_*Y_), xy = cur % (X_*Y_);
                atomicAdd(&out[((size_t)(b*C_ + lane))*(X_*Y_) + xy], acc);
                acc = 0.f; cur = cell;
            }
            acc += feat[(size_t)p*C_ + lane];
        }
    } else {
        for (int i = 0; i < n; ++i) {
            int cell = __shfl(cl, i);
            int p    = __shfl(pl, i);
            if (cell != cur) {
                int b = cur / (X_*Y_), xy = cur % (X_*Y_);
                atomicAdd(&out[((size_t)(b*C_ + lane))*(X_*Y_) + xy], acc);
                acc = 0.f; cur = cell;
            }
            acc += feat[(size_t)p*C_ + lane];
        }
    }
    int b = cur / (X_*Y_), xy = cur % (X_*Y_);
    atomicAdd(&out[((size_t)(b*C_ + lane))*(X_*Y_) + xy], acc);
}

// Fallback (tiny ws): direct atomics into (B,C,X,Y).
__global__ __launch_bounds__(256)
void scatter_fallback(const float* __restrict__ feat,
                      const int* __restrict__ rank,
                      float* __restrict__ dst) {
    int tid  = blockIdx.x * blockDim.x + threadIdx.x;
    int wave = tid >> 6;
    int lane = tid & 63;
    if (wave >= NPTS) return;
    int cell = rank[wave];
    if (cell < 0) return;
    int b = cell / (X_*Y_);
    int xy = cell % (X_*Y_);
    float v = feat[(size_t)wave*C_ + lane];
    atomicAdd(&dst[((size_t)(b*C_ + lane))*(X_*Y_) + xy], v);
}

extern "C" void kernel_launch(void* const* d_in, const int* in_sizes, int n_in,
                              void* d_out, int out_size, void* d_ws, size_t ws_size,
                              hipStream_t stream) {
    const float* feat       = (const float*)d_in[0];
    const float* post_trans = (const float*)d_in[1];
    const float* post_rots  = (const float*)d_in[2];
    const float* intr       = (const float*)d_in[3];
    const float* extr       = (const float*)d_in[4];
    const float* frustum    = (const float*)d_in[5];
    const float* bev_res    = (const float*)d_in[6];
    const float* bev_start  = (const float*)d_in[7];
    float* out = (float*)d_out;

    // ws layout
    char* base = (char*)d_ws;
    double* mats  = (double*)base;                         size_t off = 4096;
    int* rank     = (int*)(base + off);                    off += (size_t)NPTS*4;
    int* hist     = (int*)(base + off);                    off += (size_t)NCELL*4;
    int* offs     = (int*)(base + off);                    off += (size_t)(NCELL+1)*4 + 4;
    int* cursor   = (int*)(base + off);                    off += (size_t)NCELL*4;
    int* plist    = (int*)(base + off);                    off += (size_t)NPTS*4;
    int* clist    = (int*)(base + off);                    off += (size_t)NPTS*4;
    bool have_ws = (ws_size >= off);

    hipLaunchKernelGGL(prep_kernel, dim3(1), dim3(16), 0, stream,
                       post_rots, intr, extr, mats);

    const int pt_blocks = (NPTS + 255) / 256;

    hipMemsetAsync(out, 0, (size_t)out_size*sizeof(float), stream);

    if (have_ws) {
        hipMemsetAsync(hist, 0, (size_t)NCELL*4, stream);
        geom_kernel<<<pt_blocks, 256, 0, stream>>>(post_trans, frustum, bev_res,
                                                   bev_start, mats, rank, hist);
        prefix_kernel<<<1, 1024, 0, stream>>>(hist, offs, cursor);
        fill_kernel<<<pt_blocks, 256, 0, stream>>>(rank, cursor, plist, clist);
        const int nchunks = (NPTS + CHUNK - 1) / CHUNK;            // 10824 waves max
        const int gblocks = (nchunks * 64 + 255) / 256;
        gather2_kernel<<<gblocks, 256, 0, stream>>>(feat, clist, plist,
                                                    &offs[NCELL], out);
    } else {
        geom_kernel<<<pt_blocks, 256, 0, stream>>>(post_trans, frustum, bev_res,
                                                   bev_start, mats, rank, hist);
        scatter_fallback<<<(NPTS*64 + 255)/256, 256, 0, stream>>>(feat, rank, out);
    }
}

// Round 4
// 208.369 us; speedup vs baseline: 2.7709x; 1.8053x over previous
//
#include <hip/hip_runtime.h>

#define B_ 2
#define N_ 6
#define D_ 41
#define H_ 16
#define W_ 44
#define C_ 64
#define X_ 200
#define Y_ 200
#define NPTS (B_*N_*D_*H_*W_)   // 346368
#define NBN (B_*N_)             // 12
#define NCELL (B_*X_*Y_)        // 80000
#define MAT_STRIDE 24           // doubles per (b,n)
#define CHUNK 32                // sorted points per wave in gather
#define NBLK_SCAN ((NCELL+255)/256)  // 313

__device__ inline void inv3x3(const double m[9], double out[9]) {
    double a=m[0],b=m[1],c=m[2],d=m[3],e=m[4],f=m[5],g=m[6],h=m[7],i=m[8];
    double A  =  (e*i - f*h);
    double Bm = -(d*i - f*g);
    double Cm =  (d*h - e*g);
    double det = a*A + b*Bm + c*Cm;
    double id = 1.0/det;
    out[0] = A*id;   out[1] = -(b*i - c*h)*id; out[2] =  (b*f - c*e)*id;
    out[3] = Bm*id;  out[4] =  (a*i - c*g)*id; out[5] = -(a*f - c*d)*id;
    out[6] = Cm*id;  out[7] = -(a*h - b*g)*id; out[8] =  (a*e - b*d)*id;
}

// One thread per (b,n): inv(post_rots), comb = rot(inv(extr)) @ inv(K), trans.
__global__ void prep_kernel(const float* __restrict__ post_rots,
                            const float* __restrict__ intr,
                            const float* __restrict__ extr,
                            double* __restrict__ mats) {
    int bn = threadIdx.x;
    if (bn >= NBN) return;

    double pr[9], prinv[9], kk[9], kin[9];
    for (int i=0;i<9;i++) pr[i] = (double)post_rots[bn*9+i];
    inv3x3(pr, prinv);
    for (int i=0;i<9;i++) kk[i] = (double)intr[bn*9+i];
    inv3x3(kk, kin);

    double a[4][8];
    for (int i=0;i<4;i++)
        for (int j=0;j<4;j++){ a[i][j] = (double)extr[bn*16+i*4+j]; a[i][4+j] = (i==j)?1.0:0.0; }
    for (int col=0; col<4; col++){
        int piv = col; double best = fabs(a[col][col]);
        for (int r=col+1;r<4;r++){ double v=fabs(a[r][col]); if (v>best){best=v;piv=r;} }
        if (piv != col) for (int j=0;j<8;j++){ double t=a[col][j]; a[col][j]=a[piv][j]; a[piv][j]=t; }
        double ip = 1.0/a[col][col];
        for (int j=0;j<8;j++) a[col][j] *= ip;
        for (int r=0;r<4;r++){
            if (r==col) continue;
            double f = a[r][col];
            for (int j=0;j<8;j++) a[r][j] -= f*a[col][j];
        }
    }
    double rot[9], trans[3];
    for (int i=0;i<3;i++){ for (int j=0;j<3;j++) rot[i*3+j]=a[i][4+j]; trans[i]=a[i][4+3]; }
    double comb[9];
    for (int i=0;i<3;i++) for (int j=0;j<3;j++)
        comb[i*3+j] = rot[i*3+0]*kin[0+j] + rot[i*3+1]*kin[3+j] + rot[i*3+2]*kin[6+j];

    double* o = mats + (size_t)bn*MAT_STRIDE;
    for (int i=0;i<9;i++) o[i]   = prinv[i];
    for (int i=0;i<9;i++) o[9+i] = comb[i];
    for (int i=0;i<3;i++) o[18+i]= trans[i];
}

// One THREAD per point: cell id (or -1) + histogram.
__global__ __launch_bounds__(256)
void geom_kernel(const float* __restrict__ post_trans,
                 const float* __restrict__ frustum,
                 const float* __restrict__ bev_res,
                 const float* __restrict__ bev_start,
                 const double* __restrict__ mats,
                 int* __restrict__ rank, int* __restrict__ hist) {
    int p = blockIdx.x * blockDim.x + threadIdx.x;
    if (p >= NPTS) return;

    int w = p % W_; int t = p / W_;
    int h = t % H_;  t /= H_;
    int d = t % D_;  t /= D_;
    int bn = t;      int b = bn / N_;

    const double* M = mats + (size_t)bn*MAT_STRIDE;
    int fidx = ((d*H_ + h)*W_ + w)*3;
    double fx = (double)frustum[fidx+0];
    double fy = (double)frustum[fidx+1];
    double fz = (double)frustum[fidx+2];

    double px = fx - (double)post_trans[bn*3+0];
    double py = fy - (double)post_trans[bn*3+1];
    double pz = fz - (double)post_trans[bn*3+2];

    double q0 = M[0]*px + M[1]*py + M[2]*pz;
    double q1 = M[3]*px + M[4]*py + M[5]*pz;
    double q2 = M[6]*px + M[7]*py + M[8]*pz;

    double r0 = q0*q2, r1 = q1*q2, r2 = q2;

    double gx = M[9]*r0  + M[10]*r1 + M[11]*r2 + M[18];
    double gy = M[12]*r0 + M[13]*r1 + M[14]*r2 + M[19];
    double gz = M[15]*r0 + M[16]*r1 + M[17]*r2 + M[20];

    double resx = (double)bev_res[0], resy = (double)bev_res[1], resz = (double)bev_res[2];
    double sx = (double)bev_start[0] - resx*0.5;
    double sy = (double)bev_start[1] - resy*0.5;
    double sz = (double)bev_start[2] - resz*0.5;

    int cx = (int)((gx - sx)/resx);
    int cy = (int)((gy - sy)/resy);
    int cz = (int)((gz - sz)/resz);

    int cell = -1;
    if (cx >= 0 && cx < X_ && cy >= 0 && cy < Y_ && cz == 0) {
        cell = (b*X_ + cx)*Y_ + cy;
        atomicAdd(&hist[cell], 1);
    }
    rank[p] = cell;
}

// ---- 3-level hierarchical scan of hist[NCELL] -> offs/cursor ----
__global__ __launch_bounds__(256)
void scanA_kernel(const int* __restrict__ hist, int* __restrict__ bsum) {
    __shared__ int s[256];
    int i = blockIdx.x * 256 + threadIdx.x;
    s[threadIdx.x] = (i < NCELL) ? hist[i] : 0;
    __syncthreads();
    for (int o = 128; o > 0; o >>= 1) {
        if (threadIdx.x < o) s[threadIdx.x] += s[threadIdx.x + o];
        __syncthreads();
    }
    if (threadIdx.x == 0) bsum[blockIdx.x] = s[0];
}

__global__ __launch_bounds__(512)
void scanB_kernel(const int* __restrict__ bsum,
                  int* __restrict__ bofs, int* __restrict__ total_out) {
    __shared__ int s[512];
    int t = threadIdx.x;
    int v = (t < NBLK_SCAN) ? bsum[t] : 0;
    s[t] = v;
    __syncthreads();
    for (int o = 1; o < 512; o <<= 1) {
        int add = (t >= o) ? s[t - o] : 0;
        __syncthreads();
        s[t] += add;
        __syncthreads();
    }
    if (t < NBLK_SCAN) bofs[t] = s[t] - v;       // exclusive
    if (t == 511) *total_out = s[511];           // grand total -> offs[NCELL]
}

__global__ __launch_bounds__(256)
void scanC_kernel(const int* __restrict__ hist, const int* __restrict__ bofs,
                  int* __restrict__ offs, int* __restrict__ cursor) {
    __shared__ int s[256];
    int i = blockIdx.x * 256 + threadIdx.x;
    int v = (i < NCELL) ? hist[i] : 0;
    s[threadIdx.x] = v;
    __syncthreads();
    for (int o = 1; o < 256; o <<= 1) {
        int add = (threadIdx.x >= o) ? s[threadIdx.x - o] : 0;
        __syncthreads();
        s[threadIdx.x] += add;
        __syncthreads();
    }
    if (i < NCELL) {
        int excl = s[threadIdx.x] - v + bofs[blockIdx.x];
        offs[i] = excl;
        cursor[i] = excl;
    }
}

// Counting-sort: point ids AND cell ids into sorted lists.
__global__ __launch_bounds__(256)
void fill_kernel(const int* __restrict__ rank,
                 int* __restrict__ cursor,
                 int* __restrict__ plist, int* __restrict__ clist) {
    int p = blockIdx.x * blockDim.x + threadIdx.x;
    if (p >= NPTS) return;
    int cell = rank[p];
    if (cell >= 0) {
        int pos = atomicAdd(&cursor[cell], 1);
        plist[pos] = p;
        clist[pos] = cell;
    }
}

// Load-balanced segmented reduction over the sorted list.
// One wave per CHUNK sorted points; lane = channel. Flush on cell change.
__global__ __launch_bounds__(256)
void gather2_kernel(const float* __restrict__ feat,
                    const int* __restrict__ clist,
                    const int* __restrict__ plist,
                    const int* __restrict__ total_ptr,
                    float* __restrict__ out) {
    int gwave = (int)((blockIdx.x * blockDim.x + threadIdx.x) >> 6);
    int lane  = threadIdx.x & 63;
    int total = total_ptr[0];
    int i0 = gwave * CHUNK;
    if (i0 >= total) return;
    int n = min(CHUNK, total - i0);

    int cl = -1, pl = 0;
    if (lane < n) { cl = clist[i0 + lane]; pl = plist[i0 + lane]; }

    int cur = __shfl(cl, 0);
    float acc = 0.f;

    if (n == CHUNK) {
        #pragma unroll
        for (int i = 0; i < CHUNK; ++i) {
            int cell = __shfl(cl, i);
            int p    = __shfl(pl, i);
            if (cell != cur) {
                int b = cur / (X_*Y_), xy = cur % (X_*Y_);
                atomicAdd(&out[((size_t)(b*C_ + lane))*(X_*Y_) + xy], acc);
                acc = 0.f; cur = cell;
            }
            acc += feat[(size_t)p*C_ + lane];
        }
    } else {
        for (int i = 0; i < n; ++i) {
            int cell = __shfl(cl, i);
            int p    = __shfl(pl, i);
            if (cell != cur) {
                int b = cur / (X_*Y_), xy = cur % (X_*Y_);
                atomicAdd(&out[((size_t)(b*C_ + lane))*(X_*Y_) + xy], acc);
                acc = 0.f; cur = cell;
            }
            acc += feat[(size_t)p*C_ + lane];
        }
    }
    int b = cur / (X_*Y_), xy = cur % (X_*Y_);
    atomicAdd(&out[((size_t)(b*C_ + lane))*(X_*Y_) + xy], acc);
}

// Fallback (tiny ws): direct atomics into (B,C,X,Y).
__global__ __launch_bounds__(256)
void scatter_fallback(const float* __restrict__ feat,
                      const int* __restrict__ rank,
                      float* __restrict__ dst) {
    int tid  = blockIdx.x * blockDim.x + threadIdx.x;
    int wave = tid >> 6;
    int lane = tid & 63;
    if (wave >= NPTS) return;
    int cell = rank[wave];
    if (cell < 0) return;
    int b = cell / (X_*Y_);
    int xy = cell % (X_*Y_);
    float v = feat[(size_t)wave*C_ + lane];
    atomicAdd(&dst[((size_t)(b*C_ + lane))*(X_*Y_) + xy], v);
}

extern "C" void kernel_launch(void* const* d_in, const int* in_sizes, int n_in,
                              void* d_out, int out_size, void* d_ws, size_t ws_size,
                              hipStream_t stream) {
    const float* feat       = (const float*)d_in[0];
    const float* post_trans = (const float*)d_in[1];
    const float* post_rots  = (const float*)d_in[2];
    const float* intr       = (const float*)d_in[3];
    const float* extr       = (const float*)d_in[4];
    const float* frustum    = (const float*)d_in[5];
    const float* bev_res    = (const float*)d_in[6];
    const float* bev_start  = (const float*)d_in[7];
    float* out = (float*)d_out;

    // ws layout
    char* base = (char*)d_ws;
    double* mats  = (double*)base;                         size_t off = 4096;
    int* rank     = (int*)(base + off);                    off += (size_t)NPTS*4;
    int* hist     = (int*)(base + off);                    off += (size_t)NCELL*4;
    int* offs     = (int*)(base + off);                    off += (size_t)(NCELL+1)*4 + 4;
    int* cursor   = (int*)(base + off);                    off += (size_t)NCELL*4;
    int* plist    = (int*)(base + off);                    off += (size_t)NPTS*4;
    int* clist    = (int*)(base + off);                    off += (size_t)NPTS*4;
    int* bsum     = (int*)(base + off);                    off += 512*4;
    int* bofs     = (int*)(base + off);                    off += 512*4;
    bool have_ws = (ws_size >= off);

    hipLaunchKernelGGL(prep_kernel, dim3(1), dim3(16), 0, stream,
                       post_rots, intr, extr, mats);

    const int pt_blocks = (NPTS + 255) / 256;

    hipMemsetAsync(out, 0, (size_t)out_size*sizeof(float), stream);

    if (have_ws) {
        hipMemsetAsync(hist, 0, (size_t)NCELL*4, stream);
        geom_kernel<<<pt_blocks, 256, 0, stream>>>(post_trans, frustum, bev_res,
                                                   bev_start, mats, rank, hist);
        scanA_kernel<<<NBLK_SCAN, 256, 0, stream>>>(hist, bsum);
        scanB_kernel<<<1, 512, 0, stream>>>(bsum, bofs, &offs[NCELL]);
        scanC_kernel<<<NBLK_SCAN, 256, 0, stream>>>(hist, bofs, offs, cursor);
        fill_kernel<<<pt_blocks, 256, 0, stream>>>(rank, cursor, plist, clist);
        const int nchunks = (NPTS + CHUNK - 1) / CHUNK;            // 10824 waves max
        const int gblocks = (nchunks * 64 + 255) / 256;
        gather2_kernel<<<gblocks, 256, 0, stream>>>(feat, clist, plist,
                                                    &offs[NCELL], out);
    } else {
        geom_kernel<<<pt_blocks, 256, 0, stream>>>(post_trans, frustum, bev_res,
                                                   bev_start, mats, rank, hist);
        scatter_fallback<<<(NPTS*64 + 255)/256, 256, 0, stream>>>(feat, rank, out);
    }
}